// Round 12
// baseline (2139.446 us; speedup 1.0000x reference)
//
#include <hip/hip_runtime.h>
#include <hip/hip_bf16.h>

#define EPS 1e-5f

// ---------------------------------------------------------------------------
// MFMA ST-GCN, R28 = R27 + A-depth-4 pipeline in k_conv main loop.
// R27 post-mortem: ugemm consolidation neutral; conv (~600us of 1143) still
// the counter-visible mass at MfmaUtil 38.7. Stall arithmetic: per step
// 16 MFMA (~80cy) + ~35 VALU + 4 ds_read (covered) + 4 global A-loads.
// Aj3 = 1.18MB > L1 -> A is L2-hit (~200-900cy) but depth-2 gives only
// ~115-160cy issue-to-use -> ~150cy stall/step -> util 30-38% = measured.
// Fix: A depth-4 (4 named buffers, unroll-by-4, static indices), B stays
// depth-2 (LDS ~120cy, covered). +32 VGPR (84->~116), under the 170 lb3
// cap -> no occupancy change (unlike R24's 256-reg blowup).
//   Gt  : (n, 18, Trr=TIN+16, CO) bf16, c-innermost; row t'=t+8; zero guards
//   B*  : (n, CO, 18, TOUT) bf16 ; Xt/Xm : (n, 18, T, C) bf16
// fp32 accumulation everywhere.
// ---------------------------------------------------------------------------

typedef __attribute__((ext_vector_type(8))) short bf16x8;
typedef __attribute__((ext_vector_type(4))) float f32x4;
typedef __attribute__((ext_vector_type(4))) unsigned u32x4;

__device__ __forceinline__ unsigned short f2bf(float f) {
  unsigned u = __builtin_bit_cast(unsigned, f);
  u = (u + 0x7FFFu + ((u >> 16) & 1u)) >> 16;  // RNE, finite inputs
  return (unsigned short)u;
}
__device__ __forceinline__ float bf2f(unsigned short h) {
  unsigned u = (unsigned)h << 16;
  return __builtin_bit_cast(float, u);
}

// --------------------------- weight prep -----------------------------------

__global__ __launch_bounds__(256, 4) void k_transpose(
    const float* __restrict__ in, float* __restrict__ out, int rows, int cols) {
  int i = blockIdx.x * 256 + threadIdx.x;
  if (i < rows * cols) {
    int r = i / cols, c = i % cols;
    out[c * rows + r] = in[i];
  }
}

__global__ __launch_bounds__(256, 4) void k_beta(
    const float* __restrict__ bn2g, const float* __restrict__ bn2b,
    const float* __restrict__ tb, const float* __restrict__ rb,
    float* __restrict__ beta, int Co) {
  int o = blockIdx.x * 256 + threadIdx.x;
  if (o < Co)
    beta[o] = bn2g[o] * (1.0f / sqrtf(1.0f + EPS)) * tb[o] + bn2b[o] + rb[o];
}

__global__ __launch_bounds__(256, 4) void k_s1b1(
    const float* __restrict__ bn1g, const float* __restrict__ bn1b,
    const float* __restrict__ gb, float* __restrict__ s1v,
    float* __restrict__ b1p, int Co) {
  int o = blockIdx.x * 256 + threadIdx.x;
  if (o < Co) {
    float s1 = bn1g[o] * (1.0f / sqrtf(1.0f + EPS));
    s1v[o] = s1;
    b1p[o] = fmaf(s1, gb[o], bn1b[o]);
  }
}

// 9-tap conv pack (K=c per tap): out[((ot*9+j)*KCc+kc)*512 + lane*8 + jj]
// c = kc*32 + q*8 + jj, o = ot*16 + m, value tw[o][c][j]*bn2g_scale.
__global__ __launch_bounds__(256, 4) void k_pack_conv9(
    const float* __restrict__ tw, const float* __restrict__ bn2g,
    unsigned short* __restrict__ out, int CO) {
  int KCc = CO / 32;
  int total = (CO / 16) * 9 * KCc * 512;
  int i = blockIdx.x * 256 + threadIdx.x;
  if (i >= total) return;
  int jj = i & 7, lane = (i >> 3) & 63, rest = i >> 9;
  int kc = rest % KCc; rest /= KCc;
  int j = rest % 9, ot = rest / 9;
  int q = lane >> 4, m = lane & 15;
  int c = kc * 32 + q * 8 + jj, o = ot * 16 + m;
  out[i] = f2bf(tw[((size_t)o * CO + c) * 9 + j] * bn2g[o] * (1.0f / sqrtf(1.0f + EPS)));
}

// K=c pack (residual rw / channel gw): out[ot][kc][lane][8], c = kc*32+q*8+j
__global__ __launch_bounds__(256, 4) void k_pack_k32(
    const float* __restrict__ W, unsigned short* __restrict__ out, int K, int M) {
  int total = (M / 16) * (K / 32) * 512;
  int i = blockIdx.x * 256 + threadIdx.x;
  if (i >= total) return;
  int j = i & 7, lane = (i >> 3) & 63, rest = i >> 9;
  int kc = rest % (K / 32), ot = rest / (K / 32);
  int q = lane >> 4, m = lane & 15;
  int c = kc * 32 + q * 8 + j, o = ot * 16 + m;
  out[i] = f2bf(W[(size_t)o * K + c]);
}

// --------------------------- block 1 front (fused) -------------------------
// data_bn -> A-mix -> 1x1 (2->64) -> BN1+ReLU -> Gt1 (LDS-transposed,
// coalesced, left-pad 8); XB for residual.
__global__ __launch_bounds__(256, 4) void k_front1g(
    const float* __restrict__ x, const float* __restrict__ dbng,
    const float* __restrict__ dbnb, const float* __restrict__ Amat,
    const float* __restrict__ gw, const float* __restrict__ gb,
    const float* __restrict__ bn1g, const float* __restrict__ bn1b,
    unsigned short* __restrict__ Gt1, float* __restrict__ xb1) {
  int n = blockIdx.x, t0 = blockIdx.y * 64;
  __shared__ float xb[2304];  // [c][tt][v]
  __shared__ float xm[2304];  // A-mixed
  __shared__ float As[324];
  __shared__ float g0s[64], g1s[64], bps[64];
  __shared__ unsigned short ldsT[64 * 65];  // [o][tt], pad 65
  const float rs = 1.0f / sqrtf(1.0f + EPS);
  for (int e = threadIdx.x; e < 324; e += 256) As[e] = Amat[e];
  if (threadIdx.x < 64) {
    int o = threadIdx.x;
    float s1 = bn1g[o] * rs;
    g0s[o] = gw[o * 2 + 0] * s1;
    g1s[o] = gw[o * 2 + 1] * s1;
    bps[o] = fmaf(s1, gb[o], bn1b[o]);
  }
  for (int e = threadIdx.x; e < 2304; e += 256) {
    int c = e / 1152, r = e % 1152;  // r = tt*18+v
    int v = r % 18;
    xb[e] = x[(n * 2 + c) * 4608 + t0 * 18 + r] * (dbng[c * 18 + v] * rs) + dbnb[c * 18 + v];
  }
  __syncthreads();
  for (int e = threadIdx.x; e < 2304; e += 256) {
    int c = e / 1152, r = e % 1152;
    int v = r / 64, tt = r % 64;
    xb1[((size_t)(n * 2 + c) * 18 + v) * 256 + t0 + tt] = xb[c * 1152 + tt * 18 + v];
  }
  for (int e = threadIdx.x; e < 2304; e += 256) {
    int c = e / 1152, r = e % 1152;
    int tt = r / 18, v = r % 18;
    const float* xr = &xb[c * 1152 + tt * 18];
    float z = 0.0f;
#pragma unroll
    for (int w = 0; w < 18; w++) z = fmaf(As[v * 18 + w], xr[w], z);
    xm[e] = z;
  }
  __syncthreads();
  for (int v = 0; v < 18; v++) {
    for (int e = threadIdx.x; e < 4096; e += 256) {
      int o = e >> 6, tt = e & 63;
      float z = fmaf(g0s[o], xm[tt * 18 + v], fmaf(g1s[o], xm[1152 + tt * 18 + v], bps[o]));
      z = z > 0.0f ? z : 0.0f;
      ldsT[o * 65 + tt] = f2bf(z);
    }
    __syncthreads();
    for (int e = threadIdx.x; e < 4096; e += 256) {
      int tt = e >> 6, o = e & 63;  // lanes along o -> 128B contiguous
      Gt1[((size_t)(n * 18 + v) * 272 + 8 + t0 + tt) * 64 + o] = ldsT[o * 65 + tt];
    }
    __syncthreads();
  }
  if (blockIdx.y == 0 || blockIdx.y == 3) {
    int base = (blockIdx.y == 0) ? 0 : 264;  // left / right 8-row guards
    for (int e = threadIdx.x; e < 18 * 8 * 64; e += 256) {
      int v = e / 512, r = e % 512;
      int tg = base + (r >> 6), o = r & 63;
      Gt1[((size_t)(n * 18 + v) * 272 + tg) * 64 + o] = 0;
    }
  }
}

// --------------------------- A-mix on Xt -----------------------------------
template <int CO, int T>
__global__ __launch_bounds__(256, 4) void k_amixX(
    const unsigned short* __restrict__ Xt, unsigned short* __restrict__ Xm,
    const float* __restrict__ Amat) {
  int idx = blockIdx.x * 256 + threadIdx.x;
  int c = idx & (CO - 1);
  int t = (idx / CO) & (T - 1);
  int n = idx / (CO * T);
  const size_t stride = (size_t)T * CO;
  const unsigned short* bp = Xt + (size_t)n * 18 * stride + (size_t)t * CO + c;
  unsigned short* op = Xm + (size_t)n * 18 * stride + (size_t)t * CO + c;
  float xs[18];
#pragma unroll
  for (int w = 0; w < 18; w++) xs[w] = bf2f(bp[w * stride]);
#pragma unroll
  for (int v = 0; v < 18; v++) {
    float z = 0.0f;
#pragma unroll
    for (int w = 0; w < 18; w++) z = fmaf(Amat[v * 18 + w], xs[w], z);
    op[v * stride] = f2bf(z);
  }
}

// --------------------------- channel GEMM -> Gt (MFMA) ---------------------
// Gt[n,v,8+t,o] = relu(s1[o]*(gw·Xm) + b1p[o]); LDS-transposed write;
// left+right 8-row zero guards.  (R27: otg = wave-id in WG, per-wave ldsT.)
template <int CI, int CO, int TIN>
__global__ __launch_bounds__((2 * CO <= 512 ? 2 * CO : 512), 4) void k_ugemmG(
    const unsigned short* __restrict__ Xm, const unsigned short* __restrict__ Ag,
    const float* __restrict__ s1v, const float* __restrict__ b1p,
    unsigned short* __restrict__ Gt) {
  constexpr int NP = 18 * TIN;
  constexpr int Trr = TIN + 16;
  constexpr int NOTG = CO / 32;
  const int n = blockIdx.x;
  const int p0 = blockIdx.y * 32;
  const int otg = threadIdx.x >> 6;  // wave id = 2 o-tiles of 16
  const int lane = threadIdx.x & 63;
  const int q = lane >> 4, nn = lane & 15;
  constexpr int KC = CI / 32;
  const int v = p0 / TIN;
  const int tb = p0 % TIN;
  __shared__ unsigned short ldsT[NOTG * 32 * 36];  // per-wave [t'][o'], pad 36
  unsigned short* myT = &ldsT[otg * 32 * 36];
  f32x4 acc[2][2] = {};
  const unsigned short* Xn = Xm + (size_t)n * NP * CI;
  for (int kc = 0; kc < KC; kc++) {
    bf16x8 A[2];
#pragma unroll
    for (int i = 0; i < 2; i++)
      A[i] = *(const bf16x8*)(Ag + (((size_t)(otg * 2 + i) * KC + kc) * 64 + lane) * 8);
#pragma unroll
    for (int u = 0; u < 2; u++) {
      bf16x8 B = *(const bf16x8*)(Xn + (size_t)(p0 + u * 16 + nn) * CI + kc * 32 + q * 8);
#pragma unroll
      for (int i = 0; i < 2; i++)
        acc[i][u] = __builtin_amdgcn_mfma_f32_16x16x32_bf16(A[i], B, acc[i][u], 0, 0, 0);
    }
  }
#pragma unroll
  for (int i = 0; i < 2; i++) {
    int obl = i * 16 + q * 4;       // o-local in [0,32)
    int ob = otg * 32 + obl;
    const float4 s4 = *(const float4*)&s1v[ob];
    const float4 b4 = *(const float4*)&b1p[ob];
#pragma unroll
    for (int u = 0; u < 2; u++) {
      unsigned short zb[4];
#pragma unroll
      for (int r = 0; r < 4; r++) {
        float z = fmaf(acc[i][u][r], ((const float*)&s4)[r], ((const float*)&b4)[r]);
        z = z > 0.0f ? z : 0.0f;
        zb[r] = f2bf(z);
      }
      *(unsigned long long*)&myT[(u * 16 + nn) * 36 + obl] =
          *(const unsigned long long*)zb;
    }
  }
  // per-wave slice: within-wave ds_write->ds_read ordered by lgkmcnt (no bar)
  // Gt write: lanes along c -> 64B lines fully covered; rows shifted +8
  for (int e = lane; e < 1024; e += 64) {
    int tq = e >> 5, cq2 = e & 31;
    Gt[((size_t)(n * 18 + v) * Trr + 8 + tb + tq) * CO + otg * 32 + cq2] = myT[tq * 36 + cq2];
  }
  // guards: rows t' in [0,8) and [TIN+8, TIN+16), this otg's 32 channels
  if (tb == 0) {
    for (int g = 0; g < 8; g++) {
      int idx = g * 64 + lane;  // 512 = 16 rows x 32 c
      int r16 = idx >> 5, c = otg * 32 + (idx & 31);
      int tg = (r16 < 8) ? r16 : (TIN + r16);
      Gt[((size_t)(n * 18 + v) * Trr + tg) * CO + c] = 0;
    }
  }
}

// --------------------------- fused conv (MFMA, LDS-tiled B) ----------------
// Uniform 9 taps over an LDS-resident Gt tile (staged once per c-phase);
// residual 1x1 over Xt (or fp32 XB path for conv1).
// R28: main loop A depth-4 (4 named buffers, unroll-by-4; covers ~400-560cy
// L2 A-latency), B depth-2 (LDS covered). Swizzle ((tl>>1)&7)<<4 write+read.
template <int CIN, int CO, int S, int TIN, int TOUT, int OTB, int TB>
__global__ __launch_bounds__(64 * (CO / (16 * OTB)) < 256 ? 64 * (CO / (16 * OTB)) : 256, 3)
void k_conv(
    const unsigned short* __restrict__ Gt, const unsigned short* __restrict__ Xt,
    const float* __restrict__ XB, const unsigned short* __restrict__ Aj,
    const unsigned short* __restrict__ Ar, const float* __restrict__ rwT1,
    const float* __restrict__ beta, unsigned short* __restrict__ Out) {
  static_assert(TB == 2, "NT formula assumes 32 to's per block");
  constexpr int Trr = TIN + 16;
  constexpr int WAVES = CO / (16 * OTB);         // 1 / 2 / 4
  constexpr int THREADS = 64 * WAVES;
  constexpr int KCc = CO / 32;                   // global kc count (A index)
  constexpr int NT = (S == 2) ? 72 : 40;         // staged ti rows
  constexpr int NP = (NT * 2 * CO * 2 > 49152) ? 2 : 1;  // c-phases
  constexpr int CP = CO / NP;                    // channels per phase
  constexpr int KCP = CP / 32;                   // kc per phase (2/4/4)
  constexpr int LKCP = (KCP == 4) ? 2 : 1;
  constexpr int M9 = 9 * KCP;                    // steps per phase (18/36/36)
  constexpr int KCR = (CIN >= 32) ? CIN / 32 : 0;

  const int n = blockIdx.x;
  const int to_base = blockIdx.y * (16 * TB);
  const int v0 = blockIdx.z * 2;
  const int otg = threadIdx.x >> 6;
  const int lane = threadIdx.x & 63;
  const int q = lane >> 4, nn = lane & 15;
  const int ti0 = S * to_base - 4;               // first staged ti

  __shared__ unsigned short Bs[NT * 2 * CP];

  f32x4 acc[OTB][TB][2] = {};

  // ---- precomputed LDS byte bases (j=0,kcl=0) + row regs ----
  unsigned linb[TB][2];
  int tla[TB];
#pragma unroll
  for (int tb = 0; tb < TB; tb++) {
    int t0 = S * (tb * 16 + nn);
    tla[tb] = t0;
#pragma unroll
    for (int u = 0; u < 2; u++)
      linb[tb][u] = (unsigned)(((u * NT + t0) * CP + q * 8) * 2);
  }

  const unsigned short* Acp = Aj + (size_t)lane * 8;

  auto loadA = [&](int m, int ph, bf16x8 (&A)[OTB]) {
    int j = m >> LKCP, kcg = ph * KCP + (m & (KCP - 1));
#pragma unroll
    for (int i = 0; i < OTB; i++)
      A[i] = *(const bf16x8*)(Acp +
          (((size_t)(otg * OTB + i) * 9 + j) * KCc + kcg) * 512);
  };
  auto loadB = [&](int m, bf16x8 (&B)[TB][2]) {
    int j = m >> LKCP, kcl = m & (KCP - 1);
    unsigned joff = (unsigned)j * (unsigned)(CP * 2) + (unsigned)kcl * 64u;
#pragma unroll
    for (int tb = 0; tb < TB; tb++) {
      unsigned swz = ((((unsigned)(tla[tb] + j)) >> 1) & 7u) << 4;
#pragma unroll
      for (int u = 0; u < 2; u++) {
        unsigned byte = (linb[tb][u] + joff) ^ swz;
        B[tb][u] = *(const bf16x8*)((const char*)Bs + byte);
      }
    }
  };
  auto mfmaB = [&](bf16x8 (&A)[OTB], bf16x8 (&B)[TB][2]) {
#pragma unroll
    for (int i = 0; i < OTB; i++)
#pragma unroll
      for (int tb = 0; tb < TB; tb++)
#pragma unroll
        for (int u = 0; u < 2; u++)
          acc[i][tb][u] =
              __builtin_amdgcn_mfma_f32_16x16x32_bf16(A[i], B[tb][u], acc[i][tb][u],
                                                      0, 0, 0);
  };

#pragma unroll 1
  for (int ph = 0; ph < NP; ph++) {
    // ---- stage this phase's Gt tile (unique bytes, coalesced 16B) ----
    constexpr int CPC = CP / 8;
    constexpr int TOTCH = NT * 2 * CPC;          // 16B chunks
    for (int e = (int)threadIdx.x; e < TOTCH; e += THREADS) {
      int cc = e % CPC, rest = e / CPC;
      int u = rest & 1, tl = rest >> 1;
      const unsigned short* src = Gt +
          ((size_t)(n * 18 + v0 + u) * Trr + (size_t)(8 + ti0 + tl)) * CO +
          ph * CP + cc * 8;
      u32x4 d = *(const u32x4*)src;
      unsigned hb = (((unsigned)(u * NT + tl) * CP + (unsigned)cc * 8u) * 2u) ^
                    ((((unsigned)tl >> 1) & 7u) << 4);
      *(u32x4*)((char*)Bs + hb) = d;
    }
    // A prologue (depth-4) issues before the barrier: L2 latency overlaps
    // the stage drain.
    bf16x8 A0[OTB], A1[OTB], A2[OTB], A3[OTB], Ba[TB][2], Bb[TB][2];
    loadA(0, ph, A0); loadA(1, ph, A1); loadA(2, ph, A2); loadA(3, ph, A3);
    __syncthreads();
    loadB(0, Ba); loadB(1, Bb);

#pragma unroll 1
    for (int m = 0; m + 4 <= M9; m += 4) {
      mfmaB(A0, Ba);
      if (m + 4 < M9) loadA(m + 4, ph, A0);
      loadB(m + 2, Ba);
      __builtin_amdgcn_sched_barrier(0);
      mfmaB(A1, Bb);
      if (m + 5 < M9) loadA(m + 5, ph, A1);
      loadB(m + 3, Bb);
      __builtin_amdgcn_sched_barrier(0);
      mfmaB(A2, Ba);
      if (m + 6 < M9) loadA(m + 6, ph, A2);
      if (m + 4 < M9) loadB(m + 4, Ba);
      __builtin_amdgcn_sched_barrier(0);
      mfmaB(A3, Bb);
      if (m + 7 < M9) loadA(m + 7, ph, A3);
      if (m + 5 < M9) loadB(m + 5, Bb);
      __builtin_amdgcn_sched_barrier(0);
    }
    if constexpr ((M9 & 3) == 2) {  // conv1: M9=18 -> 2-step tail
      mfmaB(A0, Ba);
      __builtin_amdgcn_sched_barrier(0);
      mfmaB(A1, Bb);
      __builtin_amdgcn_sched_barrier(0);
    }
    if (ph + 1 < NP) __syncthreads();   // all reads done before next stage
  }

  if constexpr (CIN >= 32) {
    // ---- residual 1x1 over Xt, KCR even (2/4), register depth-2 ----
    unsigned r_tu[TB][2];
#pragma unroll
    for (int tb = 0; tb < TB; tb++)
#pragma unroll
      for (int u = 0; u < 2; u++) {
        int t = S * (to_base + tb * 16 + nn);
        r_tu[tb][u] = (unsigned)(((n * 18 + v0 + u) * TIN + t) * CIN + q * 8);
      }
    auto loadAr = [&](int kcr, bf16x8 (&A)[OTB]) {
#pragma unroll
      for (int i = 0; i < OTB; i++)
        A[i] = *(const bf16x8*)(Ar + (((size_t)(otg * OTB + i) * KCR + kcr) * 64 + lane) * 8);
    };
    auto loadBr = [&](int kcr, bf16x8 (&B)[TB][2]) {
#pragma unroll
      for (int tb = 0; tb < TB; tb++)
#pragma unroll
        for (int u = 0; u < 2; u++)
          B[tb][u] = *(const bf16x8*)(Xt + r_tu[tb][u] + (unsigned)kcr * 32u);
    };
    bf16x8 Ra[OTB], Sa[TB][2], Rb[OTB], Sb[TB][2];
    loadAr(0, Ra); loadBr(0, Sa);
    loadAr(1, Rb); loadBr(1, Sb);
#pragma unroll 1
    for (int kcr = 0; kcr < KCR; kcr += 2) {
      mfmaB(Ra, Sa);
      if (kcr + 2 < KCR) { loadAr(kcr + 2, Ra); loadBr(kcr + 2, Sa); }
      __builtin_amdgcn_sched_barrier(0);
      mfmaB(Rb, Sb);
      if (kcr + 3 < KCR) { loadAr(kcr + 3, Rb); loadBr(kcr + 3, Sb); }
      __builtin_amdgcn_sched_barrier(0);
    }
  } else {
#pragma unroll
    for (int ci = 0; ci < 2; ci++) {
#pragma unroll
      for (int tb = 0; tb < TB; tb++)
#pragma unroll
        for (int u = 0; u < 2; u++) {
          float xv =
              XB[(((size_t)n * 2 + ci) * 18 + v0 + u) * TIN + S * (to_base + tb * 16 + nn)];
#pragma unroll
          for (int i = 0; i < OTB; i++) {
            const float4 w4 = *(const float4*)&rwT1[ci * CO + (otg * OTB + i) * 16 + q * 4];
            acc[i][tb][u][0] = fmaf(w4.x, xv, acc[i][tb][u][0]);
            acc[i][tb][u][1] = fmaf(w4.y, xv, acc[i][tb][u][1]);
            acc[i][tb][u][2] = fmaf(w4.z, xv, acc[i][tb][u][2]);
            acc[i][tb][u][3] = fmaf(w4.w, xv, acc[i][tb][u][3]);
          }
        }
    }
  }

#pragma unroll
  for (int i = 0; i < OTB; i++) {
    int ob = (otg * OTB + i) * 16 + q * 4;
    const float4 bt = *(const float4*)&beta[ob];
#pragma unroll
    for (int tb = 0; tb < TB; tb++)
#pragma unroll
      for (int u = 0; u < 2; u++) {
        int v = v0 + u, to = to_base + tb * 16 + nn;
#pragma unroll
        for (int r = 0; r < 4; r++) {
          float val = acc[i][tb][u][r] + ((const float*)&bt)[r];
          Out[(((size_t)n * CO + ob + r) * 18 + v) * TOUT + to] =
              f2bf(val > 0.0f ? val : 0.0f);
        }
      }
  }
}

// ------------- EMA smooth (bf16 in) -> bf16 transposed emission ------------
__global__ __launch_bounds__(64) void k_smooth2(
    const unsigned short* __restrict__ X, unsigned short* __restrict__ Xt,
    int CO, int T) {
  __shared__ float tile[64 * 33];
  int n = blockIdx.x, v = blockIdx.y, c0 = blockIdx.z * 64;
  int tid = threadIdx.x;
  float s = 0.0f;
  for (int tc = 0; tc < T; tc += 32) {
    for (int e = tid; e < 64 * 32; e += 64) {
      int cc = e >> 5, tt = e & 31;
      tile[cc * 33 + tt] = bf2f(X[((size_t)(n * CO + c0 + cc) * 18 + v) * T + tc + tt]);
    }
    __syncthreads();
    float* row = &tile[tid * 33];
    int start = 0;
    if (tc == 0) { s = row[0]; start = 1; }
    for (int tt = start; tt < 32; tt++) {
      s = fmaf(0.85f, s, 0.15f * row[tt]);
      row[tt] = s;
    }
    for (int it = 0; it < 32; it++)
      Xt[((size_t)(n * 18 + v) * T + tc + it) * CO + c0 + tid] = f2bf(tile[tid * 33 + it]);
    __syncthreads();
  }
}

// in-place EMA on bf16 rows (block 3); rows contiguous length T.
__global__ __launch_bounds__(64) void k_smooth(unsigned short* __restrict__ X, int T) {
  __shared__ float tile[64 * 33];
  size_t r0 = (size_t)blockIdx.x * 64;
  float s = 0.0f;
  for (int tc = 0; tc < T; tc += 32) {
    for (int e = threadIdx.x; e < 64 * 32; e += 64) {
      int r = e >> 5, tt = e & 31;
      tile[r * 33 + tt] = bf2f(X[(r0 + r) * T + tc + tt]);
    }
    __syncthreads();
    float* row = &tile[threadIdx.x * 33];
    int start = 0;
    if (tc == 0) { s = row[0]; start = 1; }
    for (int tt = start; tt < 32; tt++) {
      s = fmaf(0.85f, s, 0.15f * row[tt]);
      row[tt] = s;
    }
    __syncthreads();
    for (int e = threadIdx.x; e < 64 * 32; e += 64) {
      int r = e >> 5, tt = e & 31;
      X[(r0 + r) * T + tc + tt] = f2bf(tile[r * 33 + tt]);
    }
    __syncthreads();
  }
}

// mean over (v,t)=1152 then 10-way FC.  H:(nc,256,18,64) bf16
__global__ __launch_bounds__(256, 4) void k_poolfc(
    const unsigned short* __restrict__ H, const float* __restrict__ fcw,
    const float* __restrict__ fcb, float* __restrict__ out) {
  int n = blockIdx.x;
  __shared__ float pool[256];
  const unsigned short* row = H + (size_t)(n * 256 + threadIdx.x) * 1152;
  float s = 0.0f;
  for (int i = 0; i < 1152; i += 8) {
    u32x4 d = *(const u32x4*)(row + i);
#pragma unroll
    for (int k = 0; k < 4; k++) {
      unsigned dv = ((const unsigned*)&d)[k];
      s += __builtin_bit_cast(float, dv << 16);
      s += __builtin_bit_cast(float, dv & 0xFFFF0000u);
    }
  }
  pool[threadIdx.x] = s * (1.0f / 1152.0f);
  __syncthreads();
  if (threadIdx.x < 10) {
    float a = fcb[threadIdx.x];
    for (int c = 0; c < 256; c++) a = fmaf(fcw[threadIdx.x * 256 + c], pool[c], a);
    out[n * 10 + threadIdx.x] = a;
  }
}

extern "C" void kernel_launch(void* const* d_in, const int* in_sizes, int n_in,
                              void* d_out, int out_size, void* d_ws, size_t ws_size,
                              hipStream_t stream) {
  const float* x    = (const float*)d_in[0];
  const float* Amat = (const float*)d_in[1];
  const float* dbng = (const float*)d_in[2];
  const float* dbnb = (const float*)d_in[3];
  const float* gw1 = (const float*)d_in[4];   const float* gb1 = (const float*)d_in[5];
  const float* bn1g1 = (const float*)d_in[6]; const float* bn1b1 = (const float*)d_in[7];
  const float* tw1 = (const float*)d_in[8];   const float* tb1 = (const float*)d_in[9];
  const float* bn2g1 = (const float*)d_in[10]; const float* bn2b1 = (const float*)d_in[11];
  const float* rw1 = (const float*)d_in[12];  const float* rb1 = (const float*)d_in[13];
  const float* gw2 = (const float*)d_in[14];  const float* gb2 = (const float*)d_in[15];
  const float* bn1g2 = (const float*)d_in[16]; const float* bn1b2 = (const float*)d_in[17];
  const float* tw2 = (const float*)d_in[18];  const float* tb2 = (const float*)d_in[19];
  const float* bn2g2 = (const float*)d_in[20]; const float* bn2b2 = (const float*)d_in[21];
  const float* rw2 = (const float*)d_in[22];  const float* rb2 = (const float*)d_in[23];
  const float* gw3 = (const float*)d_in[24];  const float* gb3 = (const float*)d_in[25];
  const float* bn1g3 = (const float*)d_in[26]; const float* bn1b3 = (const float*)d_in[27];
  const float* tw3 = (const float*)d_in[28];  const float* tb3 = (const float*)d_in[29];
  const float* bn2g3 = (const float*)d_in[30]; const float* bn2b3 = (const float*)d_in[31];
  const float* rw3 = (const float*)d_in[32];  const float* rb3 = (const float*)d_in[33];
  const float* fcw = (const float*)d_in[34];  const float* fcb = (const float*)d_in[35];
  (void)in_sizes; (void)n_in; (void)out_size;

  // ---- weights region at ws base ----
  float* f = (float*)d_ws;
  float* rwT1  = f;             // 128
  float* beta1 = rwT1 + 128;    // 64
  float* beta2 = beta1 + 64;    // 128
  float* beta3 = beta2 + 128;   // 256
  float* s1v2  = beta3 + 256;   // 128
  float* b1p2  = s1v2 + 128;    // 128
  float* s1v3  = b1p2 + 128;    // 256
  float* b1p3  = s1v3 + 256;    // 256
  // pad to 2048 floats
  unsigned short* H = (unsigned short*)(f + 2048);
  unsigned short* Aj1 = H;                 // 36864   (4*9*2*512)
  unsigned short* Aj2 = Aj1 + 36864;       // 147456  (8*9*4*512)
  unsigned short* Aj3 = Aj2 + 147456;      // 589824  (16*9*8*512)
  unsigned short* Ar2 = Aj3 + 589824;      // 8192
  unsigned short* Ar3 = Ar2 + 8192;        // 32768
  unsigned short* Ag2 = Ar3 + 32768;       // 8192
  unsigned short* Ag3 = Ag2 + 8192;        // 32768
  const size_t WOFFB = 8192 + 856064ULL * 2;  // 1,720,320 bytes (16B aligned)

  // ---- NC: fewest chunks that fit the workspace (2x64 at ws~240MB) ----
  const size_t PERN = 3723264ULL;
  long long avail = (long long)ws_size - (long long)WOFFB - 256;
  int NC = (avail > 0) ? (int)(avail / (long long)PERN) : 1;
  if (NC > 64) NC = 64;
  if (NC < 1) NC = 1;
  {
    int nch = (128 + NC - 1) / NC;
    NC = (128 + nch - 1) / nch;  // equalize chunk sizes
  }
  char* wb = (char*)d_ws;
  unsigned short* B1 = (unsigned short*)(wb + WOFFB);
  unsigned short* B2 = B1 + (size_t)NC * 294912;
  float* XB = (float*)((char*)B2 + (size_t)NC * 589824);
  unsigned short* Gt = (unsigned short*)((char*)XB + (size_t)NC * 36864);
  unsigned short* Xt = (unsigned short*)((char*)Gt + (size_t)NC * 1327104);
  unsigned short* Xm = Xt + (size_t)NC * 294912;

  // ---- weight prep (idempotent) ----
  k_transpose<<<1, 256, 0, stream>>>(rw1, rwT1, 64, 2);
  k_beta<<<1, 256, 0, stream>>>(bn2g1, bn2b1, tb1, rb1, beta1, 64);
  k_beta<<<1, 256, 0, stream>>>(bn2g2, bn2b2, tb2, rb2, beta2, 128);
  k_beta<<<1, 256, 0, stream>>>(bn2g3, bn2b3, tb3, rb3, beta3, 256);
  k_s1b1<<<1, 256, 0, stream>>>(bn1g2, bn1b2, gb2, s1v2, b1p2, 128);
  k_s1b1<<<1, 256, 0, stream>>>(bn1g3, bn1b3, gb3, s1v3, b1p3, 256);
  k_pack_conv9<<<144, 256, 0, stream>>>(tw1, bn2g1, Aj1, 64);
  k_pack_conv9<<<576, 256, 0, stream>>>(tw2, bn2g2, Aj2, 128);
  k_pack_conv9<<<2304, 256, 0, stream>>>(tw3, bn2g3, Aj3, 256);
  k_pack_k32<<<32, 256, 0, stream>>>(rw2, Ar2, 64, 128);
  k_pack_k32<<<128, 256, 0, stream>>>(rw3, Ar3, 128, 256);
  k_pack_k32<<<32, 256, 0, stream>>>(gw2, Ag2, 64, 128);
  k_pack_k32<<<128, 256, 0, stream>>>(gw3, Ag3, 128, 256);

  // ---- network per N-chunk ----
  for (int n0 = 0; n0 < 128; n0 += NC) {
    const int nc = (128 - n0 < NC) ? 128 - n0 : NC;
    // block 1
    k_front1g<<<dim3(nc, 4), 256, 0, stream>>>(
        x + (size_t)n0 * 9216, dbng, dbnb, Amat, gw1, gb1, bn1g1, bn1b1, Gt, XB);
    k_conv<2, 64, 1, 256, 256, 4, 2><<<dim3(nc, 8, 9), 64, 0, stream>>>(
        Gt, nullptr, XB, Aj1, nullptr, rwT1, beta1, B1);
    k_smooth2<<<dim3(nc, 18, 1), 64, 0, stream>>>(B1, Xt, 64, 256);
    // block 2 (ugemm: 4-wave WGs)
    k_amixX<64, 256><<<nc * 64, 256, 0, stream>>>(Xt, Xm, Amat);
    k_ugemmG<64, 128, 256><<<dim3(nc, 144), 256, 0, stream>>>(
        Xm, Ag2, s1v2, b1p2, Gt);
    k_conv<64, 128, 2, 256, 128, 4, 2><<<dim3(nc, 4, 9), 128, 0, stream>>>(
        Gt, Xt, nullptr, Aj2, Ar2, nullptr, beta2, B2);
    k_smooth2<<<dim3(nc, 18, 2), 64, 0, stream>>>(B2, Xt, 128, 128);
    // block 3 (ugemm: 8-wave WGs; output reuses B1)
    k_amixX<128, 128><<<nc * 64, 256, 0, stream>>>(Xt, Xm, Amat);
    k_ugemmG<128, 256, 128><<<dim3(nc, 72), 512, 0, stream>>>(
        Xm, Ag3, s1v3, b1p3, Gt);
    k_conv<128, 256, 2, 128, 64, 4, 2><<<dim3(nc, 2, 9), 256, 0, stream>>>(
        Gt, Xt, nullptr, Aj3, Ar3, nullptr, beta3, B1);
    k_smooth<<<nc * 72, 64, 0, stream>>>(B1, 64);
    // head
    k_poolfc<<<nc, 256, 0, stream>>>(B1, fcw, fcb, (float*)d_out + (size_t)n0 * 10);
  }
}

// Round 13
// 1139.619 us; speedup vs baseline: 1.8773x; 1.8773x over previous
//
#include <hip/hip_runtime.h>
#include <hip/hip_bf16.h>

#define EPS 1e-5f

// ---------------------------------------------------------------------------
// MFMA ST-GCN, R29 = R27 (verified 1143us) + s_setprio around MFMA clusters.
// R28 post-mortem: A-depth-4 spilled (A 64 + B 32 + acc 64 AGPR + addr ~20
// = ~180 > 170 lb3 cap) -> WRITE_SIZE 37MB -> 1.07GB scratch, MfmaUtil 6.7.
// Register-depth pipelining on A is closed BOTH directions (R24 occupancy,
// R28 spill); depth-2 at 148 regs is the feasible max. R29 applies T5:
// since R22 the conv has a phase-split schedule (stage -> barrier -> MFMA
// cluster) so co-resident waves are at different roles -- the regime where
// setprio pays (m224 +34-39%; null only on lockstep). 2 SALU/step, 0 regs.
//   Gt  : (n, 18, Trr=TIN+16, CO) bf16, c-innermost; row t'=t+8; zero guards
//   B*  : (n, CO, 18, TOUT) bf16 ; Xt/Xm : (n, 18, T, C) bf16
// fp32 accumulation everywhere.
// ---------------------------------------------------------------------------

typedef __attribute__((ext_vector_type(8))) short bf16x8;
typedef __attribute__((ext_vector_type(4))) float f32x4;
typedef __attribute__((ext_vector_type(4))) unsigned u32x4;

__device__ __forceinline__ unsigned short f2bf(float f) {
  unsigned u = __builtin_bit_cast(unsigned, f);
  u = (u + 0x7FFFu + ((u >> 16) & 1u)) >> 16;  // RNE, finite inputs
  return (unsigned short)u;
}
__device__ __forceinline__ float bf2f(unsigned short h) {
  unsigned u = (unsigned)h << 16;
  return __builtin_bit_cast(float, u);
}

// --------------------------- weight prep -----------------------------------

__global__ __launch_bounds__(256, 4) void k_transpose(
    const float* __restrict__ in, float* __restrict__ out, int rows, int cols) {
  int i = blockIdx.x * 256 + threadIdx.x;
  if (i < rows * cols) {
    int r = i / cols, c = i % cols;
    out[c * rows + r] = in[i];
  }
}

__global__ __launch_bounds__(256, 4) void k_beta(
    const float* __restrict__ bn2g, const float* __restrict__ bn2b,
    const float* __restrict__ tb, const float* __restrict__ rb,
    float* __restrict__ beta, int Co) {
  int o = blockIdx.x * 256 + threadIdx.x;
  if (o < Co)
    beta[o] = bn2g[o] * (1.0f / sqrtf(1.0f + EPS)) * tb[o] + bn2b[o] + rb[o];
}

__global__ __launch_bounds__(256, 4) void k_s1b1(
    const float* __restrict__ bn1g, const float* __restrict__ bn1b,
    const float* __restrict__ gb, float* __restrict__ s1v,
    float* __restrict__ b1p, int Co) {
  int o = blockIdx.x * 256 + threadIdx.x;
  if (o < Co) {
    float s1 = bn1g[o] * (1.0f / sqrtf(1.0f + EPS));
    s1v[o] = s1;
    b1p[o] = fmaf(s1, gb[o], bn1b[o]);
  }
}

// 9-tap conv pack (K=c per tap): out[((ot*9+j)*KCc+kc)*512 + lane*8 + jj]
// c = kc*32 + q*8 + jj, o = ot*16 + m, value tw[o][c][j]*bn2g_scale.
__global__ __launch_bounds__(256, 4) void k_pack_conv9(
    const float* __restrict__ tw, const float* __restrict__ bn2g,
    unsigned short* __restrict__ out, int CO) {
  int KCc = CO / 32;
  int total = (CO / 16) * 9 * KCc * 512;
  int i = blockIdx.x * 256 + threadIdx.x;
  if (i >= total) return;
  int jj = i & 7, lane = (i >> 3) & 63, rest = i >> 9;
  int kc = rest % KCc; rest /= KCc;
  int j = rest % 9, ot = rest / 9;
  int q = lane >> 4, m = lane & 15;
  int c = kc * 32 + q * 8 + jj, o = ot * 16 + m;
  out[i] = f2bf(tw[((size_t)o * CO + c) * 9 + j] * bn2g[o] * (1.0f / sqrtf(1.0f + EPS)));
}

// K=c pack (residual rw / channel gw): out[ot][kc][lane][8], c = kc*32+q*8+j
__global__ __launch_bounds__(256, 4) void k_pack_k32(
    const float* __restrict__ W, unsigned short* __restrict__ out, int K, int M) {
  int total = (M / 16) * (K / 32) * 512;
  int i = blockIdx.x * 256 + threadIdx.x;
  if (i >= total) return;
  int j = i & 7, lane = (i >> 3) & 63, rest = i >> 9;
  int kc = rest % (K / 32), ot = rest / (K / 32);
  int q = lane >> 4, m = lane & 15;
  int c = kc * 32 + q * 8 + j, o = ot * 16 + m;
  out[i] = f2bf(W[(size_t)o * K + c]);
}

// --------------------------- block 1 front (fused) -------------------------
// data_bn -> A-mix -> 1x1 (2->64) -> BN1+ReLU -> Gt1 (LDS-transposed,
// coalesced, left-pad 8); XB for residual.
__global__ __launch_bounds__(256, 4) void k_front1g(
    const float* __restrict__ x, const float* __restrict__ dbng,
    const float* __restrict__ dbnb, const float* __restrict__ Amat,
    const float* __restrict__ gw, const float* __restrict__ gb,
    const float* __restrict__ bn1g, const float* __restrict__ bn1b,
    unsigned short* __restrict__ Gt1, float* __restrict__ xb1) {
  int n = blockIdx.x, t0 = blockIdx.y * 64;
  __shared__ float xb[2304];  // [c][tt][v]
  __shared__ float xm[2304];  // A-mixed
  __shared__ float As[324];
  __shared__ float g0s[64], g1s[64], bps[64];
  __shared__ unsigned short ldsT[64 * 65];  // [o][tt], pad 65
  const float rs = 1.0f / sqrtf(1.0f + EPS);
  for (int e = threadIdx.x; e < 324; e += 256) As[e] = Amat[e];
  if (threadIdx.x < 64) {
    int o = threadIdx.x;
    float s1 = bn1g[o] * rs;
    g0s[o] = gw[o * 2 + 0] * s1;
    g1s[o] = gw[o * 2 + 1] * s1;
    bps[o] = fmaf(s1, gb[o], bn1b[o]);
  }
  for (int e = threadIdx.x; e < 2304; e += 256) {
    int c = e / 1152, r = e % 1152;  // r = tt*18+v
    int v = r % 18;
    xb[e] = x[(n * 2 + c) * 4608 + t0 * 18 + r] * (dbng[c * 18 + v] * rs) + dbnb[c * 18 + v];
  }
  __syncthreads();
  for (int e = threadIdx.x; e < 2304; e += 256) {
    int c = e / 1152, r = e % 1152;
    int v = r / 64, tt = r % 64;
    xb1[((size_t)(n * 2 + c) * 18 + v) * 256 + t0 + tt] = xb[c * 1152 + tt * 18 + v];
  }
  for (int e = threadIdx.x; e < 2304; e += 256) {
    int c = e / 1152, r = e % 1152;
    int tt = r / 18, v = r % 18;
    const float* xr = &xb[c * 1152 + tt * 18];
    float z = 0.0f;
#pragma unroll
    for (int w = 0; w < 18; w++) z = fmaf(As[v * 18 + w], xr[w], z);
    xm[e] = z;
  }
  __syncthreads();
  for (int v = 0; v < 18; v++) {
    for (int e = threadIdx.x; e < 4096; e += 256) {
      int o = e >> 6, tt = e & 63;
      float z = fmaf(g0s[o], xm[tt * 18 + v], fmaf(g1s[o], xm[1152 + tt * 18 + v], bps[o]));
      z = z > 0.0f ? z : 0.0f;
      ldsT[o * 65 + tt] = f2bf(z);
    }
    __syncthreads();
    for (int e = threadIdx.x; e < 4096; e += 256) {
      int tt = e >> 6, o = e & 63;  // lanes along o -> 128B contiguous
      Gt1[((size_t)(n * 18 + v) * 272 + 8 + t0 + tt) * 64 + o] = ldsT[o * 65 + tt];
    }
    __syncthreads();
  }
  if (blockIdx.y == 0 || blockIdx.y == 3) {
    int base = (blockIdx.y == 0) ? 0 : 264;  // left / right 8-row guards
    for (int e = threadIdx.x; e < 18 * 8 * 64; e += 256) {
      int v = e / 512, r = e % 512;
      int tg = base + (r >> 6), o = r & 63;
      Gt1[((size_t)(n * 18 + v) * 272 + tg) * 64 + o] = 0;
    }
  }
}

// --------------------------- A-mix on Xt -----------------------------------
template <int CO, int T>
__global__ __launch_bounds__(256, 4) void k_amixX(
    const unsigned short* __restrict__ Xt, unsigned short* __restrict__ Xm,
    const float* __restrict__ Amat) {
  int idx = blockIdx.x * 256 + threadIdx.x;
  int c = idx & (CO - 1);
  int t = (idx / CO) & (T - 1);
  int n = idx / (CO * T);
  const size_t stride = (size_t)T * CO;
  const unsigned short* bp = Xt + (size_t)n * 18 * stride + (size_t)t * CO + c;
  unsigned short* op = Xm + (size_t)n * 18 * stride + (size_t)t * CO + c;
  float xs[18];
#pragma unroll
  for (int w = 0; w < 18; w++) xs[w] = bf2f(bp[w * stride]);
#pragma unroll
  for (int v = 0; v < 18; v++) {
    float z = 0.0f;
#pragma unroll
    for (int w = 0; w < 18; w++) z = fmaf(Amat[v * 18 + w], xs[w], z);
    op[v * stride] = f2bf(z);
  }
}

// --------------------------- channel GEMM -> Gt (MFMA) ---------------------
// Gt[n,v,8+t,o] = relu(s1[o]*(gw·Xm) + b1p[o]); LDS-transposed write;
// left+right 8-row zero guards.  (R27: otg = wave-id in WG, per-wave ldsT.)
template <int CI, int CO, int TIN>
__global__ __launch_bounds__((2 * CO <= 512 ? 2 * CO : 512), 4) void k_ugemmG(
    const unsigned short* __restrict__ Xm, const unsigned short* __restrict__ Ag,
    const float* __restrict__ s1v, const float* __restrict__ b1p,
    unsigned short* __restrict__ Gt) {
  constexpr int NP = 18 * TIN;
  constexpr int Trr = TIN + 16;
  constexpr int NOTG = CO / 32;
  const int n = blockIdx.x;
  const int p0 = blockIdx.y * 32;
  const int otg = threadIdx.x >> 6;  // wave id = 2 o-tiles of 16
  const int lane = threadIdx.x & 63;
  const int q = lane >> 4, nn = lane & 15;
  constexpr int KC = CI / 32;
  const int v = p0 / TIN;
  const int tb = p0 % TIN;
  __shared__ unsigned short ldsT[NOTG * 32 * 36];  // per-wave [t'][o'], pad 36
  unsigned short* myT = &ldsT[otg * 32 * 36];
  f32x4 acc[2][2] = {};
  const unsigned short* Xn = Xm + (size_t)n * NP * CI;
  for (int kc = 0; kc < KC; kc++) {
    bf16x8 A[2];
#pragma unroll
    for (int i = 0; i < 2; i++)
      A[i] = *(const bf16x8*)(Ag + (((size_t)(otg * 2 + i) * KC + kc) * 64 + lane) * 8);
#pragma unroll
    for (int u = 0; u < 2; u++) {
      bf16x8 B = *(const bf16x8*)(Xn + (size_t)(p0 + u * 16 + nn) * CI + kc * 32 + q * 8);
#pragma unroll
      for (int i = 0; i < 2; i++)
        acc[i][u] = __builtin_amdgcn_mfma_f32_16x16x32_bf16(A[i], B, acc[i][u], 0, 0, 0);
    }
  }
#pragma unroll
  for (int i = 0; i < 2; i++) {
    int obl = i * 16 + q * 4;       // o-local in [0,32)
    int ob = otg * 32 + obl;
    const float4 s4 = *(const float4*)&s1v[ob];
    const float4 b4 = *(const float4*)&b1p[ob];
#pragma unroll
    for (int u = 0; u < 2; u++) {
      unsigned short zb[4];
#pragma unroll
      for (int r = 0; r < 4; r++) {
        float z = fmaf(acc[i][u][r], ((const float*)&s4)[r], ((const float*)&b4)[r]);
        z = z > 0.0f ? z : 0.0f;
        zb[r] = f2bf(z);
      }
      *(unsigned long long*)&myT[(u * 16 + nn) * 36 + obl] =
          *(const unsigned long long*)zb;
    }
  }
  // per-wave slice: within-wave ds_write->ds_read ordered by lgkmcnt (no bar)
  // Gt write: lanes along c -> 64B lines fully covered; rows shifted +8
  for (int e = lane; e < 1024; e += 64) {
    int tq = e >> 5, cq2 = e & 31;
    Gt[((size_t)(n * 18 + v) * Trr + 8 + tb + tq) * CO + otg * 32 + cq2] = myT[tq * 36 + cq2];
  }
  // guards: rows t' in [0,8) and [TIN+8, TIN+16), this otg's 32 channels
  if (tb == 0) {
    for (int g = 0; g < 8; g++) {
      int idx = g * 64 + lane;  // 512 = 16 rows x 32 c
      int r16 = idx >> 5, c = otg * 32 + (idx & 31);
      int tg = (r16 < 8) ? r16 : (TIN + r16);
      Gt[((size_t)(n * 18 + v) * Trr + tg) * CO + c] = 0;
    }
  }
}

// --------------------------- fused conv (MFMA, LDS-tiled B) ----------------
// Uniform 9 taps over an LDS-resident Gt tile (staged once per c-phase);
// residual 1x1 over Xt (or fp32 XB path for conv1).
// Swizzle ((tl>>1)&7)<<4 on write AND read; precomputed linb/tla addressing.
// A register depth-2 (the feasible max: R24/R28 closed deeper options).
// R29: s_setprio(1) around MFMA clusters (T5; phase-split regime).
template <int CIN, int CO, int S, int TIN, int TOUT, int OTB, int TB>
__global__ __launch_bounds__(64 * (CO / (16 * OTB)) < 256 ? 64 * (CO / (16 * OTB)) : 256, 3)
void k_conv(
    const unsigned short* __restrict__ Gt, const unsigned short* __restrict__ Xt,
    const float* __restrict__ XB, const unsigned short* __restrict__ Aj,
    const unsigned short* __restrict__ Ar, const float* __restrict__ rwT1,
    const float* __restrict__ beta, unsigned short* __restrict__ Out) {
  static_assert(TB == 2, "NT formula assumes 32 to's per block");
  constexpr int Trr = TIN + 16;
  constexpr int WAVES = CO / (16 * OTB);         // 1 / 2 / 4
  constexpr int THREADS = 64 * WAVES;
  constexpr int KCc = CO / 32;                   // global kc count (A index)
  constexpr int NT = (S == 2) ? 72 : 40;         // staged ti rows
  constexpr int NP = (NT * 2 * CO * 2 > 49152) ? 2 : 1;  // c-phases
  constexpr int CP = CO / NP;                    // channels per phase
  constexpr int KCP = CP / 32;                   // kc per phase (2/4/4)
  constexpr int LKCP = (KCP == 4) ? 2 : 1;
  constexpr int M9 = 9 * KCP;                    // steps per phase (18/36/36)
  constexpr int KCR = (CIN >= 32) ? CIN / 32 : 0;

  const int n = blockIdx.x;
  const int to_base = blockIdx.y * (16 * TB);
  const int v0 = blockIdx.z * 2;
  const int otg = threadIdx.x >> 6;
  const int lane = threadIdx.x & 63;
  const int q = lane >> 4, nn = lane & 15;
  const int ti0 = S * to_base - 4;               // first staged ti

  __shared__ unsigned short Bs[NT * 2 * CP];

  f32x4 acc[OTB][TB][2] = {};

  // ---- precomputed LDS byte bases (j=0,kcl=0) + row regs ----
  unsigned linb[TB][2];
  int tla[TB];
#pragma unroll
  for (int tb = 0; tb < TB; tb++) {
    int t0 = S * (tb * 16 + nn);
    tla[tb] = t0;
#pragma unroll
    for (int u = 0; u < 2; u++)
      linb[tb][u] = (unsigned)(((u * NT + t0) * CP + q * 8) * 2);
  }

  const unsigned short* Acp = Aj + (size_t)lane * 8;

  auto loadA = [&](int m, int ph, bf16x8 (&A)[OTB]) {
    int j = m >> LKCP, kcg = ph * KCP + (m & (KCP - 1));
#pragma unroll
    for (int i = 0; i < OTB; i++)
      A[i] = *(const bf16x8*)(Acp +
          (((size_t)(otg * OTB + i) * 9 + j) * KCc + kcg) * 512);
  };
  auto loadB = [&](int m, bf16x8 (&B)[TB][2]) {
    int j = m >> LKCP, kcl = m & (KCP - 1);
    unsigned joff = (unsigned)j * (unsigned)(CP * 2) + (unsigned)kcl * 64u;
#pragma unroll
    for (int tb = 0; tb < TB; tb++) {
      unsigned swz = ((((unsigned)(tla[tb] + j)) >> 1) & 7u) << 4;
#pragma unroll
      for (int u = 0; u < 2; u++) {
        unsigned byte = (linb[tb][u] + joff) ^ swz;
        B[tb][u] = *(const bf16x8*)((const char*)Bs + byte);
      }
    }
  };
  auto mfmaB = [&](bf16x8 (&A)[OTB], bf16x8 (&B)[TB][2]) {
    __builtin_amdgcn_s_setprio(1);
#pragma unroll
    for (int i = 0; i < OTB; i++)
#pragma unroll
      for (int tb = 0; tb < TB; tb++)
#pragma unroll
        for (int u = 0; u < 2; u++)
          acc[i][tb][u] =
              __builtin_amdgcn_mfma_f32_16x16x32_bf16(A[i], B[tb][u], acc[i][tb][u],
                                                      0, 0, 0);
    __builtin_amdgcn_s_setprio(0);
  };

#pragma unroll 1
  for (int ph = 0; ph < NP; ph++) {
    // ---- stage this phase's Gt tile (unique bytes, coalesced 16B) ----
    constexpr int CPC = CP / 8;
    constexpr int TOTCH = NT * 2 * CPC;          // 16B chunks
    for (int e = (int)threadIdx.x; e < TOTCH; e += THREADS) {
      int cc = e % CPC, rest = e / CPC;
      int u = rest & 1, tl = rest >> 1;
      const unsigned short* src = Gt +
          ((size_t)(n * 18 + v0 + u) * Trr + (size_t)(8 + ti0 + tl)) * CO +
          ph * CP + cc * 8;
      u32x4 d = *(const u32x4*)src;
      unsigned hb = (((unsigned)(u * NT + tl) * CP + (unsigned)cc * 8u) * 2u) ^
                    ((((unsigned)tl >> 1) & 7u) << 4);
      *(u32x4*)((char*)Bs + hb) = d;
    }
    __syncthreads();

    // ---- depth-2 pipelined compute over M9 steps (M9 even) ----
    bf16x8 Aa[OTB], Ba[TB][2], Ab[OTB], Bb[TB][2];
    loadA(0, ph, Aa); loadB(0, Ba);
    loadA(1, ph, Ab); loadB(1, Bb);
#pragma unroll 1
    for (int m = 0; m < M9; m += 2) {
      mfmaB(Aa, Ba);
      if (m + 2 < M9) { loadA(m + 2, ph, Aa); loadB(m + 2, Ba); }
      __builtin_amdgcn_sched_barrier(0);
      mfmaB(Ab, Bb);
      if (m + 3 < M9) { loadA(m + 3, ph, Ab); loadB(m + 3, Bb); }
      __builtin_amdgcn_sched_barrier(0);
    }
    if (ph + 1 < NP) __syncthreads();   // all reads done before next stage
  }

  if constexpr (CIN >= 32) {
    // ---- residual 1x1 over Xt, KCR even (2/4), register depth-2 ----
    unsigned r_tu[TB][2];
#pragma unroll
    for (int tb = 0; tb < TB; tb++)
#pragma unroll
      for (int u = 0; u < 2; u++) {
        int t = S * (to_base + tb * 16 + nn);
        r_tu[tb][u] = (unsigned)(((n * 18 + v0 + u) * TIN + t) * CIN + q * 8);
      }
    auto loadAr = [&](int kcr, bf16x8 (&A)[OTB]) {
#pragma unroll
      for (int i = 0; i < OTB; i++)
        A[i] = *(const bf16x8*)(Ar + (((size_t)(otg * OTB + i) * KCR + kcr) * 64 + lane) * 8);
    };
    auto loadBr = [&](int kcr, bf16x8 (&B)[TB][2]) {
#pragma unroll
      for (int tb = 0; tb < TB; tb++)
#pragma unroll
        for (int u = 0; u < 2; u++)
          B[tb][u] = *(const bf16x8*)(Xt + r_tu[tb][u] + (unsigned)kcr * 32u);
    };
    bf16x8 Ra[OTB], Sa[TB][2], Rb[OTB], Sb[TB][2];
    loadAr(0, Ra); loadBr(0, Sa);
    loadAr(1, Rb); loadBr(1, Sb);
#pragma unroll 1
    for (int kcr = 0; kcr < KCR; kcr += 2) {
      mfmaB(Ra, Sa);
      if (kcr + 2 < KCR) { loadAr(kcr + 2, Ra); loadBr(kcr + 2, Sa); }
      __builtin_amdgcn_sched_barrier(0);
      mfmaB(Rb, Sb);
      if (kcr + 3 < KCR) { loadAr(kcr + 3, Rb); loadBr(kcr + 3, Sb); }
      __builtin_amdgcn_sched_barrier(0);
    }
  } else {
#pragma unroll
    for (int ci = 0; ci < 2; ci++) {
#pragma unroll
      for (int tb = 0; tb < TB; tb++)
#pragma unroll
        for (int u = 0; u < 2; u++) {
          float xv =
              XB[(((size_t)n * 2 + ci) * 18 + v0 + u) * TIN + S * (to_base + tb * 16 + nn)];
#pragma unroll
          for (int i = 0; i < OTB; i++) {
            const float4 w4 = *(const float4*)&rwT1[ci * CO + (otg * OTB + i) * 16 + q * 4];
            acc[i][tb][u][0] = fmaf(w4.x, xv, acc[i][tb][u][0]);
            acc[i][tb][u][1] = fmaf(w4.y, xv, acc[i][tb][u][1]);
            acc[i][tb][u][2] = fmaf(w4.z, xv, acc[i][tb][u][2]);
            acc[i][tb][u][3] = fmaf(w4.w, xv, acc[i][tb][u][3]);
          }
        }
    }
  }

#pragma unroll
  for (int i = 0; i < OTB; i++) {
    int ob = (otg * OTB + i) * 16 + q * 4;
    const float4 bt = *(const float4*)&beta[ob];
#pragma unroll
    for (int tb = 0; tb < TB; tb++)
#pragma unroll
      for (int u = 0; u < 2; u++) {
        int v = v0 + u, to = to_base + tb * 16 + nn;
#pragma unroll
        for (int r = 0; r < 4; r++) {
          float val = acc[i][tb][u][r] + ((const float*)&bt)[r];
          Out[(((size_t)n * CO + ob + r) * 18 + v) * TOUT + to] =
              f2bf(val > 0.0f ? val : 0.0f);
        }
      }
  }
}

// ------------- EMA smooth (bf16 in) -> bf16 transposed emission ------------
__global__ __launch_bounds__(64) void k_smooth2(
    const unsigned short* __restrict__ X, unsigned short* __restrict__ Xt,
    int CO, int T) {
  __shared__ float tile[64 * 33];
  int n = blockIdx.x, v = blockIdx.y, c0 = blockIdx.z * 64;
  int tid = threadIdx.x;
  float s = 0.0f;
  for (int tc = 0; tc < T; tc += 32) {
    for (int e = tid; e < 64 * 32; e += 64) {
      int cc = e >> 5, tt = e & 31;
      tile[cc * 33 + tt] = bf2f(X[((size_t)(n * CO + c0 + cc) * 18 + v) * T + tc + tt]);
    }
    __syncthreads();
    float* row = &tile[tid * 33];
    int start = 0;
    if (tc == 0) { s = row[0]; start = 1; }
    for (int tt = start; tt < 32; tt++) {
      s = fmaf(0.85f, s, 0.15f * row[tt]);
      row[tt] = s;
    }
    for (int it = 0; it < 32; it++)
      Xt[((size_t)(n * 18 + v) * T + tc + it) * CO + c0 + tid] = f2bf(tile[tid * 33 + it]);
    __syncthreads();
  }
}

// in-place EMA on bf16 rows (block 3); rows contiguous length T.
__global__ __launch_bounds__(64) void k_smooth(unsigned short* __restrict__ X, int T) {
  __shared__ float tile[64 * 33];
  size_t r0 = (size_t)blockIdx.x * 64;
  float s = 0.0f;
  for (int tc = 0; tc < T; tc += 32) {
    for (int e = threadIdx.x; e < 64 * 32; e += 64) {
      int r = e >> 5, tt = e & 31;
      tile[r * 33 + tt] = bf2f(X[(r0 + r) * T + tc + tt]);
    }
    __syncthreads();
    float* row = &tile[threadIdx.x * 33];
    int start = 0;
    if (tc == 0) { s = row[0]; start = 1; }
    for (int tt = start; tt < 32; tt++) {
      s = fmaf(0.85f, s, 0.15f * row[tt]);
      row[tt] = s;
    }
    __syncthreads();
    for (int e = threadIdx.x; e < 64 * 32; e += 64) {
      int r = e >> 5, tt = e & 31;
      X[(r0 + r) * T + tc + tt] = f2bf(tile[r * 33 + tt]);
    }
    __syncthreads();
  }
}

// mean over (v,t)=1152 then 10-way FC.  H:(nc,256,18,64) bf16
__global__ __launch_bounds__(256, 4) void k_poolfc(
    const unsigned short* __restrict__ H, const float* __restrict__ fcw,
    const float* __restrict__ fcb, float* __restrict__ out) {
  int n = blockIdx.x;
  __shared__ float pool[256];
  const unsigned short* row = H + (size_t)(n * 256 + threadIdx.x) * 1152;
  float s = 0.0f;
  for (int i = 0; i < 1152; i += 8) {
    u32x4 d = *(const u32x4*)(row + i);
#pragma unroll
    for (int k = 0; k < 4; k++) {
      unsigned dv = ((const unsigned*)&d)[k];
      s += __builtin_bit_cast(float, dv << 16);
      s += __builtin_bit_cast(float, dv & 0xFFFF0000u);
    }
  }
  pool[threadIdx.x] = s * (1.0f / 1152.0f);
  __syncthreads();
  if (threadIdx.x < 10) {
    float a = fcb[threadIdx.x];
    for (int c = 0; c < 256; c++) a = fmaf(fcw[threadIdx.x * 256 + c], pool[c], a);
    out[n * 10 + threadIdx.x] = a;
  }
}

extern "C" void kernel_launch(void* const* d_in, const int* in_sizes, int n_in,
                              void* d_out, int out_size, void* d_ws, size_t ws_size,
                              hipStream_t stream) {
  const float* x    = (const float*)d_in[0];
  const float* Amat = (const float*)d_in[1];
  const float* dbng = (const float*)d_in[2];
  const float* dbnb = (const float*)d_in[3];
  const float* gw1 = (const float*)d_in[4];   const float* gb1 = (const float*)d_in[5];
  const float* bn1g1 = (const float*)d_in[6]; const float* bn1b1 = (const float*)d_in[7];
  const float* tw1 = (const float*)d_in[8];   const float* tb1 = (const float*)d_in[9];
  const float* bn2g1 = (const float*)d_in[10]; const float* bn2b1 = (const float*)d_in[11];
  const float* rw1 = (const float*)d_in[12];  const float* rb1 = (const float*)d_in[13];
  const float* gw2 = (const float*)d_in[14];  const float* gb2 = (const float*)d_in[15];
  const float* bn1g2 = (const float*)d_in[16]; const float* bn1b2 = (const float*)d_in[17];
  const float* tw2 = (const float*)d_in[18];  const float* tb2 = (const float*)d_in[19];
  const float* bn2g2 = (const float*)d_in[20]; const float* bn2b2 = (const float*)d_in[21];
  const float* rw2 = (const float*)d_in[22];  const float* rb2 = (const float*)d_in[23];
  const float* gw3 = (const float*)d_in[24];  const float* gb3 = (const float*)d_in[25];
  const float* bn1g3 = (const float*)d_in[26]; const float* bn1b3 = (const float*)d_in[27];
  const float* tw3 = (const float*)d_in[28];  const float* tb3 = (const float*)d_in[29];
  const float* bn2g3 = (const float*)d_in[30]; const float* bn2b3 = (const float*)d_in[31];
  const float* rw3 = (const float*)d_in[32];  const float* rb3 = (const float*)d_in[33];
  const float* fcw = (const float*)d_in[34];  const float* fcb = (const float*)d_in[35];
  (void)in_sizes; (void)n_in; (void)out_size;

  // ---- weights region at ws base ----
  float* f = (float*)d_ws;
  float* rwT1  = f;             // 128
  float* beta1 = rwT1 + 128;    // 64
  float* beta2 = beta1 + 64;    // 128
  float* beta3 = beta2 + 128;   // 256
  float* s1v2  = beta3 + 256;   // 128
  float* b1p2  = s1v2 + 128;    // 128
  float* s1v3  = b1p2 + 128;    // 256
  float* b1p3  = s1v3 + 256;    // 256
  // pad to 2048 floats
  unsigned short* H = (unsigned short*)(f + 2048);
  unsigned short* Aj1 = H;                 // 36864   (4*9*2*512)
  unsigned short* Aj2 = Aj1 + 36864;       // 147456  (8*9*4*512)
  unsigned short* Aj3 = Aj2 + 147456;      // 589824  (16*9*8*512)
  unsigned short* Ar2 = Aj3 + 589824;      // 8192
  unsigned short* Ar3 = Ar2 + 8192;        // 32768
  unsigned short* Ag2 = Ar3 + 32768;       // 8192
  unsigned short* Ag3 = Ag2 + 8192;        // 32768
  const size_t WOFFB = 8192 + 856064ULL * 2;  // 1,720,320 bytes (16B aligned)

  // ---- NC: fewest chunks that fit the workspace (2x64 at ws~240MB) ----
  const size_t PERN = 3723264ULL;
  long long avail = (long long)ws_size - (long long)WOFFB - 256;
  int NC = (avail > 0) ? (int)(avail / (long long)PERN) : 1;
  if (NC > 64) NC = 64;
  if (NC < 1) NC = 1;
  {
    int nch = (128 + NC - 1) / NC;
    NC = (128 + nch - 1) / nch;  // equalize chunk sizes
  }
  char* wb = (char*)d_ws;
  unsigned short* B1 = (unsigned short*)(wb + WOFFB);
  unsigned short* B2 = B1 + (size_t)NC * 294912;
  float* XB = (float*)((char*)B2 + (size_t)NC * 589824);
  unsigned short* Gt = (unsigned short*)((char*)XB + (size_t)NC * 36864);
  unsigned short* Xt = (unsigned short*)((char*)Gt + (size_t)NC * 1327104);
  unsigned short* Xm = Xt + (size_t)NC * 294912;

  // ---- weight prep (idempotent) ----
  k_transpose<<<1, 256, 0, stream>>>(rw1, rwT1, 64, 2);
  k_beta<<<1, 256, 0, stream>>>(bn2g1, bn2b1, tb1, rb1, beta1, 64);
  k_beta<<<1, 256, 0, stream>>>(bn2g2, bn2b2, tb2, rb2, beta2, 128);
  k_beta<<<1, 256, 0, stream>>>(bn2g3, bn2b3, tb3, rb3, beta3, 256);
  k_s1b1<<<1, 256, 0, stream>>>(bn1g2, bn1b2, gb2, s1v2, b1p2, 128);
  k_s1b1<<<1, 256, 0, stream>>>(bn1g3, bn1b3, gb3, s1v3, b1p3, 256);
  k_pack_conv9<<<144, 256, 0, stream>>>(tw1, bn2g1, Aj1, 64);
  k_pack_conv9<<<576, 256, 0, stream>>>(tw2, bn2g2, Aj2, 128);
  k_pack_conv9<<<2304, 256, 0, stream>>>(tw3, bn2g3, Aj3, 256);
  k_pack_k32<<<32, 256, 0, stream>>>(rw2, Ar2, 64, 128);
  k_pack_k32<<<128, 256, 0, stream>>>(rw3, Ar3, 128, 256);
  k_pack_k32<<<32, 256, 0, stream>>>(gw2, Ag2, 64, 128);
  k_pack_k32<<<128, 256, 0, stream>>>(gw3, Ag3, 128, 256);

  // ---- network per N-chunk ----
  for (int n0 = 0; n0 < 128; n0 += NC) {
    const int nc = (128 - n0 < NC) ? 128 - n0 : NC;
    // block 1
    k_front1g<<<dim3(nc, 4), 256, 0, stream>>>(
        x + (size_t)n0 * 9216, dbng, dbnb, Amat, gw1, gb1, bn1g1, bn1b1, Gt, XB);
    k_conv<2, 64, 1, 256, 256, 4, 2><<<dim3(nc, 8, 9), 64, 0, stream>>>(
        Gt, nullptr, XB, Aj1, nullptr, rwT1, beta1, B1);
    k_smooth2<<<dim3(nc, 18, 1), 64, 0, stream>>>(B1, Xt, 64, 256);
    // block 2 (ugemm: 4-wave WGs)
    k_amixX<64, 256><<<nc * 64, 256, 0, stream>>>(Xt, Xm, Amat);
    k_ugemmG<64, 128, 256><<<dim3(nc, 144), 256, 0, stream>>>(
        Xm, Ag2, s1v2, b1p2, Gt);
    k_conv<64, 128, 2, 256, 128, 4, 2><<<dim3(nc, 4, 9), 128, 0, stream>>>(
        Gt, Xt, nullptr, Aj2, Ar2, nullptr, beta2, B2);
    k_smooth2<<<dim3(nc, 18, 2), 64, 0, stream>>>(B2, Xt, 128, 128);
    // block 3 (ugemm: 8-wave WGs; output reuses B1)
    k_amixX<128, 128><<<nc * 64, 256, 0, stream>>>(Xt, Xm, Amat);
    k_ugemmG<128, 256, 128><<<dim3(nc, 72), 512, 0, stream>>>(
        Xm, Ag3, s1v3, b1p3, Gt);
    k_conv<128, 256, 2, 128, 64, 4, 2><<<dim3(nc, 2, 9), 256, 0, stream>>>(
        Gt, Xt, nullptr, Aj3, Ar3, nullptr, beta3, B1);
    k_smooth<<<nc * 72, 64, 0, stream>>>(B1, 64);
    // head
    k_poolfc<<<nc, 256, 0, stream>>>(B1, fcw, fcb, (float*)d_out + (size_t)n0 * 10);
  }
}